// Round 13
// baseline (95.971 us; speedup 1.0000x reference)
//
#include <hip/hip_runtime.h>
#include <math.h>

// Problem dims (fixed by reference setup_inputs)
#define B 2
#define C 128
#define H 128
#define W 256
#define K 20
#define HW (H * W)

typedef float f32x4 __attribute__((ext_vector_type(4)));
typedef short bf16x8 __attribute__((ext_vector_type(8)));

__device__ __forceinline__ unsigned f2bf_bits(float x) {
    unsigned u = __float_as_uint(x);
    return (u + 0x7FFFu + ((u >> 16) & 1u)) >> 16;
}
__device__ __forceinline__ float bf_to_f(unsigned bits) {
    return __uint_as_float(bits << 16);
}

// ---------------- Kernel A: prep (R12-verified) ----------------
// blocks 0..8191: 4 waves x 1 W-row norm each; B*C*H = 32768 rows total
// block 8192:     pnf_ws = bf16 prototypes in MFMA B-fragment order (R5-verified),
//                 ppsum_ws[k] = sum_c bf(pn[k,c])^2
__global__ __launch_bounds__(256) void isomax_prep(
    const float* __restrict__ feats, const float* __restrict__ protos,
    float* __restrict__ rn_ws, short* __restrict__ pnf_ws, float* __restrict__ ppsum_ws)
{
    const int tid = threadIdx.x, wave = tid >> 6, lane = tid & 63;
    const int blk = blockIdx.x;

    if (blk < 8192) {
        const int r = blk * 4 + wave;  // row id = (b*C + c)*H + h, 32768 rows
        const float4 v = ((const float4*)(feats + (size_t)r * W))[lane];
        float ss = fmaf(v.x, v.x, fmaf(v.y, v.y, fmaf(v.z, v.z, v.w * v.w)));
        #pragma unroll
        for (int off = 32; off > 0; off >>= 1) ss += __shfl_xor(ss, off, 64);
        if (lane == 0) {
            const int h  = r & (H - 1);
            const int bc = r >> 7;
            const int c  = bc & (C - 1);
            const int b  = bc >> 7;
            rn_ws[(b * H + h) * C + c] = 1.0f / fmaxf(sqrtf(ss), 1e-12f);
        }
    } else {
        __shared__ float s_rp[32];
        for (int k = wave; k < K; k += 4) {
            const float* p = protos + k * C;
            float a = p[lane], bq = p[lane + 64];
            float ss = fmaf(a, a, bq * bq);
            #pragma unroll
            for (int off = 32; off > 0; off >>= 1) ss += __shfl_xor(ss, off, 64);
            if (lane == 0) s_rp[k] = 1.0f / fmaxf(sqrtf(ss), 1e-12f);
        }
        __syncthreads();
        for (int i = tid; i < 4096; i += 256) {
            const int j  = i & 7;
            const int ln = (i >> 3) & 63;
            const int ch = (i >> 9) & 3;
            const int t  = i >> 11;
            const int c  = ch * 32 + ((ln >> 4) & 3) * 8 + j;
            const int k  = t * 16 + (ln & 15);
            float val = (k < K) ? protos[k * C + c] * s_rp[k] : 0.0f;
            pnf_ws[i] = (short)f2bf_bits(val);
        }
        if (tid < 32) {
            float s = 0.f;
            if (tid < K) {
                const float rp = s_rp[tid];
                for (int c = 0; c < C; ++c) {
                    float pb = bf_to_f(f2bf_bits(protos[tid * C + c] * rp));
                    s = fmaf(pb, pb, s);
                }
            }
            ppsum_ws[tid] = s;
        }
    }
}

// ---------------- Kernel B: dist — BARRIER-FREE ----------------
// Grid = B*H*4 = 1024 blocks x 256 thr (4 waves). Wave = one 16-w m-tile,
// fully independent: all 128 c, 8 MFMAs, zero __syncthreads, 256 B LDS
// (per-wave S scratch; in-wave ds ordering via lgkmcnt). A-frags gathered
// direct from global (R7-verified); rn/ppsum per-lane loads (L1-broadcast).
// D stored straight from accumulators as float4 (C/D map: row=quad*4+r -> w,
// col=l16 -> k; 4 consecutive w per lane).
__global__ __launch_bounds__(256, 8) void isomax_dist(
    const float* __restrict__ feats, const float* __restrict__ rn_ws,
    const short* __restrict__ pnf_ws, const float* __restrict__ ppsum_ws,
    const float* __restrict__ dscale, float* __restrict__ out)
{
    __shared__ float s_S[4][16];   // per-wave scratch, wave-local only

    const int tid  = threadIdx.x;
    const int wave = tid >> 6, lane = tid & 63;
    const int quad = lane >> 4, l16 = lane & 15;
    const int blk  = blockIdx.x;
    const int bh   = blk >> 2;
    const int q4   = blk & 3;
    const int b    = bh >> 7, h = bh & 127;
    const int w0   = q4 * 64 + wave * 16;   // this wave's m-tile base

    // B-fragments (R5-verified packed layout): 8x 16B lane loads
    bf16x8 bfr[4][2];
    #pragma unroll
    for (int t = 0; t < 2; ++t)
        #pragma unroll
        for (int ch = 0; ch < 4; ++ch)
            bfr[ch][t] = ((const bf16x8*)pnf_ws)[(t * 4 + ch) * 64 + lane];

    const float scale = fabsf(dscale[0]);
    const float pcol0 = ppsum_ws[l16];
    const float pcol1 = ppsum_ws[16 + (l16 & 3)];

    // A-frag gather + MFMA (R7-verified mapping): af[j] <-> c = ch*32+quad*8+j
    const float* fbase = feats + (size_t)b * C * HW + h * W + w0 + l16;
    const float* rnb   = rn_ws + bh * C;
    f32x4 acc0 = {0.f, 0.f, 0.f, 0.f}, acc1 = {0.f, 0.f, 0.f, 0.f};
    float Sp = 0.f;
    #pragma unroll
    for (int ch = 0; ch < 4; ++ch) {
        bf16x8 af;
        #pragma unroll
        for (int j = 0; j < 8; ++j) {
            const int c = ch * 32 + quad * 8 + j;
            const float uf = fbase[(size_t)c * HW] * rnb[c];
            const unsigned bits = f2bf_bits(uf);
            af[j] = (short)bits;
            const float ur = bf_to_f(bits);
            Sp = fmaf(ur, ur, Sp);
        }
        acc0 = __builtin_amdgcn_mfma_f32_16x16x32_bf16(af, bfr[ch][0], acc0, 0, 0, 0);
        acc1 = __builtin_amdgcn_mfma_f32_16x16x32_bf16(af, bfr[ch][1], acc1, 0, 0, 0);
    }

    // S[w]: quad partials -> full sum per l16; broadcast via wave-local LDS
    Sp += __shfl_xor(Sp, 16, 64);
    Sp += __shfl_xor(Sp, 32, 64);
    if (lane < 16) s_S[wave][lane] = Sp;        // same-wave write...
    const float4 Sm4 = *(const float4*)&s_S[wave][quad * 4];   // ...then read (lgkmcnt)

    // Direct epilogue: lane (quad,l16) holds D[m=quad*4+r][n=l16]
    float4 o0;
    #pragma unroll
    for (int r = 0; r < 4; ++r) {
        const float d2 = fmaxf((&Sm4.x)[r] + pcol0 - 2.0f * acc0[r], 0.f);
        (&o0.x)[r] = -scale * sqrtf(d2);
    }
    *(float4*)(out + ((size_t)(b * K + l16)) * HW + h * W + w0 + quad * 4) = o0;

    if (l16 < 4) {   // k = 16 + l16
        float4 o1;
        #pragma unroll
        for (int r = 0; r < 4; ++r) {
            const float d2 = fmaxf((&Sm4.x)[r] + pcol1 - 2.0f * acc1[r], 0.f);
            (&o1.x)[r] = -scale * sqrtf(d2);
        }
        *(float4*)(out + ((size_t)(b * K + 16 + l16)) * HW + h * W + w0 + quad * 4) = o1;
    }
}

extern "C" void kernel_launch(void* const* d_in, const int* in_sizes, int n_in,
                              void* d_out, int out_size, void* d_ws, size_t ws_size,
                              hipStream_t stream) {
    const float* feats  = (const float*)d_in[0];
    const float* protos = (const float*)d_in[1];
    const float* dscale = (const float*)d_in[2];
    float* out = (float*)d_out;

    float* rn_ws    = (float*)d_ws;            // 32768 floats [b*H+h][c]
    float* ppsum_ws = rn_ws + 32768;           // 32 floats
    short* pnf_ws   = (short*)(ppsum_ws + 32); // 4096 bf16 fragment-packed

    isomax_prep<<<8193, 256, 0, stream>>>(feats, protos, rn_ws, pnf_ws, ppsum_ws);
    isomax_dist<<<B * H * 4, 256, 0, stream>>>(feats, rn_ws, pnf_ws, ppsum_ws,
                                               dscale, out);
}

// Round 14
// 87.537 us; speedup vs baseline: 1.0963x; 1.0963x over previous
//
#include <hip/hip_runtime.h>
#include <math.h>

// Problem dims (fixed by reference setup_inputs)
#define B 2
#define C 128
#define H 128
#define W 256
#define K 20
#define HW (H * W)

typedef float f32x4 __attribute__((ext_vector_type(4)));
typedef short bf16x8 __attribute__((ext_vector_type(8)));

__device__ __forceinline__ unsigned f2bf_bits(float x) {
    unsigned u = __float_as_uint(x);
    return (u + 0x7FFFu + ((u >> 16) & 1u)) >> 16;
}
__device__ __forceinline__ float bf_to_f(unsigned bits) {
    return __uint_as_float(bits << 16);
}

// One block per (b,h): 1024 threads = 16 waves; wave = 16-w m-tile (m0 = wave*16).
// R9 pipeline (best measured: phase-P + batched staging + 64KB swizzled tile +
// MFMA) with R13's verified direct-store epilogue and wave-local S broadcast:
// ONE barrier total, no s_o transpose, LDS 66 KB.
__global__ __launch_bounds__(1024) void isomax_fused(
    const float* __restrict__ feats, const float* __restrict__ protos,
    const float* __restrict__ dscale, float* __restrict__ out)
{
    __shared__ __align__(16) unsigned s_u32[C * 128];   // 64 KB bf16 tile [c][(w^swz)/2]
    __shared__ float s_rp[32];              // proto inv-norms
    __shared__ float s_pp[32];              // sum_c bf(pn[k,c])^2
    __shared__ float s_S[16][16];           // per-wave S scratch (wave-local)

    const int tid  = threadIdx.x;
    const int wave = tid >> 6, lane = tid & 63;
    const int quad = lane >> 4, l16 = lane & 15;
    const int bh   = blockIdx.x;
    const int b    = bh >> 7, h = bh & 127;
    const int m0   = wave * 16;

    const float* fb = feats + (size_t)b * C * HW + h * W;

    // ---- Issue group-A feature loads (4 rows) + proto loads, all independent ----
    const int cA = wave * 8;
    float4 fA[4];
    #pragma unroll
    for (int r = 0; r < 4; ++r)
        fA[r] = ((const float4*)(fb + (size_t)(cA + r) * HW))[lane];

    const int k0 = wave;                 // < 16 < K, always valid
    const int k1 = 16 + (wave & 3);      // uniform; only waves 0..3 store results
    const float pa0 = protos[k0 * C + lane], pb0 = protos[k0 * C + lane + 64];
    const float pa1 = protos[k1 * C + lane], pb1 = protos[k1 * C + lane + 64];

    // ---- Issue group-B feature loads before any reduction work ----
    const int cB = cA + 4;
    float4 fB[4];
    #pragma unroll
    for (int r = 0; r < 4; ++r)
        fB[r] = ((const float4*)(fb + (size_t)(cB + r) * HW))[lane];

    // ---- Phase P: two interleaved proto-norm chains (R9-verbatim) ----
    {
        float ss0 = fmaf(pa0, pa0, pb0 * pb0);
        float ss1 = fmaf(pa1, pa1, pb1 * pb1);
        #pragma unroll
        for (int off = 32; off > 0; off >>= 1) {
            ss0 += __shfl_xor(ss0, off, 64);
            ss1 += __shfl_xor(ss1, off, 64);
        }
        const float rp0 = 1.0f / fmaxf(sqrtf(ss0), 1e-12f);
        const float rp1 = 1.0f / fmaxf(sqrtf(ss1), 1e-12f);
        const float q00 = bf_to_f(f2bf_bits(pa0 * rp0));
        const float q01 = bf_to_f(f2bf_bits(pb0 * rp0));
        const float q10 = bf_to_f(f2bf_bits(pa1 * rp1));
        const float q11 = bf_to_f(f2bf_bits(pb1 * rp1));
        float s20 = fmaf(q00, q00, q01 * q01);
        float s21 = fmaf(q10, q10, q11 * q11);
        #pragma unroll
        for (int off = 32; off > 0; off >>= 1) {
            s20 += __shfl_xor(s20, off, 64);
            s21 += __shfl_xor(s21, off, 64);
        }
        if (lane == 0) {
            s_rp[k0] = rp0; s_pp[k0] = s20;
            if (wave < 4) { s_rp[k1] = rp1; s_pp[k1] = s21; }
        }
    }

    // ---- Stage both groups: interleaved shuffle chains, swizzled tile (R9-verbatim) ----
    #define PROC_GROUP(fR, c0)                                                     \
    {                                                                              \
        float ss[4];                                                               \
        _Pragma("unroll")                                                          \
        for (int r = 0; r < 4; ++r) {                                              \
            const float4 v = fR[r];                                                \
            ss[r] = fmaf(v.x, v.x, fmaf(v.y, v.y, fmaf(v.z, v.z, v.w * v.w)));     \
        }                                                                          \
        _Pragma("unroll")                                                          \
        for (int off = 32; off > 0; off >>= 1) {                                   \
            _Pragma("unroll")                                                      \
            for (int r = 0; r < 4; ++r) ss[r] += __shfl_xor(ss[r], off, 64);       \
        }                                                                          \
        _Pragma("unroll")                                                          \
        for (int r = 0; r < 4; ++r) {                                              \
            const float rn = 1.0f / fmaxf(sqrtf(ss[r]), 1e-12f);                   \
            const float4 v = fR[r];                                                \
            const unsigned lo = f2bf_bits(v.x * rn) | (f2bf_bits(v.y * rn) << 16); \
            const unsigned hi = f2bf_bits(v.z * rn) | (f2bf_bits(v.w * rn) << 16); \
            const int c = (c0) + r;                                                \
            const int word = c * 128 + ((lane * 2) ^ (((c >> 3) & 3) << 3));       \
            uint2 pk; pk.x = lo; pk.y = hi;                                        \
            *(uint2*)&s_u32[word] = pk;                                            \
        }                                                                          \
    }

    PROC_GROUP(fA, cA)
    PROC_GROUP(fB, cB)
    __syncthreads();   // THE one barrier: tile + s_rp/s_pp ready

    // ---- B-fragments from L2-hot protos (R9-verbatim mapping) ----
    bf16x8 bfrag[4][2];
    #pragma unroll
    for (int t = 0; t < 2; ++t) {
        const int k = t * 16 + l16;
        const float rp = (k < K) ? s_rp[k] : 0.0f;
        #pragma unroll
        for (int ch = 0; ch < 4; ++ch) {
            bf16x8 f = {0, 0, 0, 0, 0, 0, 0, 0};
            if (k < K) {
                const float* pr = protos + k * C + ch * 32 + quad * 8;
                const float4 pa = *(const float4*)(pr);
                const float4 pb = *(const float4*)(pr + 4);
                f[0] = (short)f2bf_bits(pa.x * rp);
                f[1] = (short)f2bf_bits(pa.y * rp);
                f[2] = (short)f2bf_bits(pa.z * rp);
                f[3] = (short)f2bf_bits(pa.w * rp);
                f[4] = (short)f2bf_bits(pb.x * rp);
                f[5] = (short)f2bf_bits(pb.y * rp);
                f[6] = (short)f2bf_bits(pb.z * rp);
                f[7] = (short)f2bf_bits(pb.w * rp);
            }
            bfrag[ch][t] = f;
        }
    }

    // ---- MFMA: A-frags from tile (R8/R9-verified addressing), 8 MFMAs ----
    f32x4 acc0 = {0.f, 0.f, 0.f, 0.f}, acc1 = {0.f, 0.f, 0.f, 0.f};
    float Sp = 0.f;
    const int wadrw = ((m0 + l16) >> 1) ^ (quad << 3);
    const unsigned sel = (unsigned)(l16 & 1);
    #pragma unroll
    for (int ch = 0; ch < 4; ++ch) {
        bf16x8 af;
        #pragma unroll
        for (int j = 0; j < 8; ++j) {
            const int rowi = ch * 32 + quad * 8 + j;
            const unsigned v = s_u32[rowi * 128 + wadrw];
            af[j] = (short)(sel ? (v >> 16) : v);
            const float ur = __uint_as_float(sel ? (v & 0xffff0000u) : (v << 16));
            Sp = fmaf(ur, ur, Sp);
        }
        acc0 = __builtin_amdgcn_mfma_f32_16x16x32_bf16(af, bfrag[ch][0], acc0, 0, 0, 0);
        acc1 = __builtin_amdgcn_mfma_f32_16x16x32_bf16(af, bfrag[ch][1], acc1, 0, 0, 0);
    }

    // ---- S[w]: quad partials -> per-wave LDS broadcast (R13-verified, no barrier) ----
    Sp += __shfl_xor(Sp, 16, 64);
    Sp += __shfl_xor(Sp, 32, 64);
    if (lane < 16) s_S[wave][lane] = Sp;                      // same-wave write...
    const float4 Sm4 = *(const float4*)&s_S[wave][quad * 4];  // ...read via lgkmcnt

    // ---- Direct epilogue (R13-verified): lane (quad,l16) = D[m=quad*4+r][n=l16] ----
    const float scale = fabsf(dscale[0]);
    const float pcol0 = s_pp[l16];
    float4 o0;
    #pragma unroll
    for (int r = 0; r < 4; ++r) {
        const float d2 = fmaxf((&Sm4.x)[r] + pcol0 - 2.0f * acc0[r], 0.f);
        (&o0.x)[r] = -scale * sqrtf(d2);
    }
    *(float4*)(out + ((size_t)(b * K + l16)) * HW + h * W + m0 + quad * 4) = o0;

    if (l16 < 4) {   // k = 16 + l16
        const float pcol1 = s_pp[16 + l16];
        float4 o1;
        #pragma unroll
        for (int r = 0; r < 4; ++r) {
            const float d2 = fmaxf((&Sm4.x)[r] + pcol1 - 2.0f * acc1[r], 0.f);
            (&o1.x)[r] = -scale * sqrtf(d2);
        }
        *(float4*)(out + ((size_t)(b * K + 16 + l16)) * HW + h * W + m0 + quad * 4) = o1;
    }
}

extern "C" void kernel_launch(void* const* d_in, const int* in_sizes, int n_in,
                              void* d_out, int out_size, void* d_ws, size_t ws_size,
                              hipStream_t stream) {
    const float* feats  = (const float*)d_in[0];
    const float* protos = (const float*)d_in[1];
    const float* dscale = (const float*)d_in[2];
    float* out = (float*)d_out;

    isomax_fused<<<B * H, 1024, 0, stream>>>(feats, protos, dscale, out);
}